// Round 4
// baseline (218.885 us; speedup 1.0000x reference)
//
#include <hip/hip_runtime.h>
#include <math.h>

static constexpr int BB  = 64;
static constexpr int DIN = 5000;
static constexpr int NHID = 1000;
static constexpr int NG  = 512;
static constexpr int NK  = 8;
static constexpr int NM  = 32;
static constexpr int GS  = 512;
static constexpr int NC  = NK * GS;   // 4096
static constexpr int NPAIR = BB * NK; // 512

// split-K GEMM configs
static constexpr int S1 = 23, CHD1 = 224, IT1 = 16, IP1 = 1024;
static constexpr int S2 = 16, CHD2 = 64,  IT2 = 8,  IP2 = 512;

// part[s][b][i] = sum_{d in chunk s} A[b,d] * Bm[i,d]
__global__ __launch_bounds__(256) void gemm64(
    const float* __restrict__ A, int lda,
    const float* __restrict__ Bm, int ldb, int Ireal,
    float* __restrict__ part, int Ipad, int Itiles, int D, int CHD)
{
  __shared__ __align__(16) float xT[32][64];
  __shared__ __align__(16) float wT[32][64];
  const int tid = threadIdx.x;
  const int itile = blockIdx.x % Itiles;
  const int s = blockIdx.x / Itiles;
  const int d_beg = s * CHD;
  const int d_end = min(D, d_beg + CHD);
  const int tx = tid & 15;
  const int ty = tid >> 4;
  float acc[4][4] = {};

  for (int d0 = d_beg; d0 < d_end; d0 += 32) {
#pragma unroll
    for (int q = 0; q < 2; q++) {
      int lin = q * 256 + tid;
      int r = lin >> 3;
      int c4 = (lin & 7) << 2;
      int d = d0 + c4;
      const float* pr = A + (size_t)r * lda;
      float4 v = make_float4(0.f, 0.f, 0.f, 0.f);
      if (d + 4 <= d_end) v = *(const float4*)(pr + d);
      else {
        if (d + 0 < d_end) v.x = pr[d + 0];
        if (d + 1 < d_end) v.y = pr[d + 1];
        if (d + 2 < d_end) v.z = pr[d + 2];
        if (d + 3 < d_end) v.w = pr[d + 3];
      }
      xT[c4 + 0][r] = v.x; xT[c4 + 1][r] = v.y;
      xT[c4 + 2][r] = v.z; xT[c4 + 3][r] = v.w;
    }
#pragma unroll
    for (int q = 0; q < 2; q++) {
      int lin = q * 256 + tid;
      int r = lin >> 3;
      int c4 = (lin & 7) << 2;
      int ib = itile * 64 + r;
      int d = d0 + c4;
      float4 v = make_float4(0.f, 0.f, 0.f, 0.f);
      if (ib < Ireal) {
        const float* pr = Bm + (size_t)ib * ldb;
        if (d + 4 <= d_end) v = *(const float4*)(pr + d);
        else {
          if (d + 0 < d_end) v.x = pr[d + 0];
          if (d + 1 < d_end) v.y = pr[d + 1];
          if (d + 2 < d_end) v.z = pr[d + 2];
          if (d + 3 < d_end) v.w = pr[d + 3];
        }
      }
      wT[c4 + 0][r] = v.x; wT[c4 + 1][r] = v.y;
      wT[c4 + 2][r] = v.z; wT[c4 + 3][r] = v.w;
    }
    __syncthreads();
    const int nn = min(32, d_end - d0);
    if (nn == 32) {
#pragma unroll
      for (int dd = 0; dd < 32; dd++) {
        float4 xv = *(const float4*)&xT[dd][tx << 2];
        float4 wv = *(const float4*)&wT[dd][ty << 2];
        float xr[4] = {xv.x, xv.y, xv.z, xv.w};
        float wr[4] = {wv.x, wv.y, wv.z, wv.w};
#pragma unroll
        for (int a = 0; a < 4; a++)
#pragma unroll
          for (int c = 0; c < 4; c++)
            acc[a][c] = fmaf(xr[a], wr[c], acc[a][c]);
      }
    } else {
      for (int dd = 0; dd < nn; dd++) {
        float4 xv = *(const float4*)&xT[dd][tx << 2];
        float4 wv = *(const float4*)&wT[dd][ty << 2];
        float xr[4] = {xv.x, xv.y, xv.z, xv.w};
        float wr[4] = {wv.x, wv.y, wv.z, wv.w};
#pragma unroll
        for (int a = 0; a < 4; a++)
#pragma unroll
          for (int c = 0; c < 4; c++)
            acc[a][c] = fmaf(xr[a], wr[c], acc[a][c]);
      }
    }
    __syncthreads();
  }

  const int b0 = tx << 2;
  const int i0 = itile * 64 + (ty << 2);
#pragma unroll
  for (int a = 0; a < 4; a++) {
    float4 vv = make_float4(acc[a][0], acc[a][1], acc[a][2], acc[a][3]);
    *(float4*)&part[((size_t)s * BB + (b0 + a)) * Ipad + i0] = vv;
  }
}

__global__ void reduce_act(const float* __restrict__ part, int S, int Ipad, int Ireal,
                           const float* __restrict__ bias, float* __restrict__ out,
                           int ostride, int mode)
{
  int lin = blockIdx.x * blockDim.x + threadIdx.x;
  int n = BB * Ireal;
  if (lin >= n) return;
  int b = lin / Ireal;
  int i = lin - b * Ireal;
  float sum = bias[i];
  for (int s = 0; s < S; s++) sum += part[((size_t)s * BB + b) * Ipad + i];
  if (mode == 0) sum = fmaxf(sum, 0.f);
  else           sum = 1.f / (1.f + expf(-sum));
  out[(size_t)b * ostride + i] = sum;
}

// Fused: per-sample top-8 (+BCE term2), then counting sort of the 512 pairs
// by (group, pair idx), then slot build (runs of <=8 pairs sharing a group).
// One 512-thread block; fully deterministic.
__global__ __launch_bounds__(512) void prep512(
    const float* __restrict__ y, const float* __restrict__ gl,
    int* __restrict__ order, int* __restrict__ sg, int* __restrict__ sstart,
    int* __restrict__ scnt, int* __restrict__ Sn, float* __restrict__ acc)
{
  __shared__ int gs[NPAIR];
  __shared__ int flag[NPAIR];
  const int tid = threadIdx.x;
  const int w = tid >> 6, lane = tid & 63;

  // phase A: top-8 + loss2, wave w handles samples 8w..8w+7
  float l2 = 0.f;
  for (int bs = 0; bs < 8; bs++) {
    const int b = w * 8 + bs;
    float v[8];
#pragma unroll
    for (int j = 0; j < 8; j++) {
      int pos = j * 64 + lane;
      float z = y[b * NG + pos];
      v[j] = z;
      float t = gl[b * NG + pos];
      l2 += fmaxf(z, 0.f) + log1pf(expf(-fabsf(z))) - z * t;
    }
    for (int k = 0; k < 8; k++) {
      float bv = -INFINITY;
      int bi = 0x7fffffff;
#pragma unroll
      for (int j = 0; j < 8; j++) {
        int pos = j * 64 + lane;
        if (v[j] > bv) { bv = v[j]; bi = pos; }
      }
#pragma unroll
      for (int off = 32; off >= 1; off >>= 1) {
        float ov = __shfl_xor(bv, off, 64);
        int   oi = __shfl_xor(bi, off, 64);
        if (ov > bv || (ov == bv && oi < bi)) { bv = ov; bi = oi; }
      }
      if (lane == 0) gs[b * NK + k] = bi;
      if (lane == (bi & 63)) {
        int jj = bi >> 6;
#pragma unroll
        for (int j = 0; j < 8; j++) if (j == jj) v[j] = -INFINITY;
      }
    }
  }
#pragma unroll
  for (int off = 32; off >= 1; off >>= 1) l2 += __shfl_xor(l2, off, 64);
  if (lane == 0) atomicAdd(acc + 1, l2);
  __syncthreads();

  // phase B: counting sort + slot build
  const int i = tid;
  const int g = gs[i];
  int pos = 0, first = 0, m = 0;
  for (int j = 0; j < NPAIR; j++) {
    int gj = gs[j];
    int lt = (gj < g);
    pos += lt | ((gj == g) & (j < i));
    first += lt;
    m += (gj == g);
  }
  const int runpos = pos - first;
  const int isS = ((runpos & 7) == 0) ? 1 : 0;
  flag[pos] = isS;
  order[pos] = i;
  __syncthreads();
  int slot = 0;
  for (int p = 0; p < pos; p++) slot += flag[p];
  if (isS) {
    sg[slot] = g;
    sstart[slot] = pos;
    scnt[slot] = min(8, m - runpos);
  }
  if (pos == NPAIR - 1) Sn[0] = slot + isS;
}

// slot-based scoring: item L = (slot s, eighth e8). Block streams 64 emb rows
// (registers) once, dots vs up to 8 samples' y staged in LDS. Uniform work.
__global__ __launch_bounds__(256) void score5(
    const float* __restrict__ emb, const float* __restrict__ y,
    const int* __restrict__ order, const int* __restrict__ sg,
    const int* __restrict__ sstart, const int* __restrict__ scnt,
    const int* __restrict__ Sn, const int* __restrict__ cands,
    const float* __restrict__ labels, const int* __restrict__ group_y,
    float* __restrict__ out, float* __restrict__ acc)
{
  const int S_n = Sn[0];
  const int T = S_n * 8;
  const int Q = (T + 7) >> 3;
  const int c = blockIdx.x & 7;
  const int r = blockIdx.x >> 3;
  if (r >= Q) return;
  const int L = c * Q + r;
  if (L >= T) return;
  const int s = L >> 3, e8 = L & 7;
  const int g = sg[s], pc = scnt[s], base = sstart[s];

  __shared__ __align__(16) float yl[8][NG];  // 16 KB
  __shared__ int cid[64];
  __shared__ int plist[8];
  __shared__ int tgt[8][NM];
  __shared__ float red[4];
  const int tid = threadIdx.x;
  if (tid < 8 && tid < pc) plist[tid] = order[base + tid];
  if (tid >= 64 && tid < 128) cid[tid - 64] = group_y[g * GS + e8 * 64 + (tid - 64)];
  __syncthreads();
  {
    int p = tid >> 5, j = tid & 31;
    if (p < pc) {
      int b = plist[p] >> 3;
      const float4* src = (const float4*)(y + (size_t)b * NG);
      float4* dst = (float4*)yl[p];
      dst[j] = src[j]; dst[j + 32] = src[j + 32];
      dst[j + 64] = src[j + 64]; dst[j + 96] = src[j + 96];
      tgt[p][j] = labels[b * NM + j] > 0.5f ? cands[b * NM + j] : -1;
    }
  }
  __syncthreads();

  const int l = tid & 15, lg = tid >> 4;  // 16 groups of 16 lanes
  float lossp = 0.f;
  for (int it = 0; it < 4; it++) {
    const int rloc = it * 16 + lg;       // 0..63
    const int row = e8 * 64 + rloc;
    const int rid = cid[rloc];
    const float4* ep = (const float4*)(emb + (size_t)rid * NG);
    float4 e[8];
#pragma unroll
    for (int seg = 0; seg < 8; seg++) e[seg] = ep[seg * 16 + l];
    for (int p = 0; p < pc; p++) {
      const float4* yp = (const float4*)yl[p];
      float sum = 0.f;
#pragma unroll
      for (int seg = 0; seg < 8; seg++) {
        float4 yv = yp[seg * 16 + l];
        sum = fmaf(e[seg].x, yv.x, sum);
        sum = fmaf(e[seg].y, yv.y, sum);
        sum = fmaf(e[seg].z, yv.z, sum);
        sum = fmaf(e[seg].w, yv.w, sum);
      }
      sum += __shfl_xor(sum, 1, 64);
      sum += __shfl_xor(sum, 2, 64);
      sum += __shfl_xor(sum, 4, 64);
      sum += __shfl_xor(sum, 8, 64);
      if (l == 0) {
        int pair = plist[p];
        out[(size_t)pair * GS + row] = sum;
        float nl = 0.f;
#pragma unroll
        for (int mm = 0; mm < NM; mm++) if (rid == tgt[p][mm]) nl = 1.f;
        lossp += fmaxf(sum, 0.f) + log1pf(expf(-fabsf(sum))) - sum * nl;
      }
    }
  }
#pragma unroll
  for (int off = 32; off >= 1; off >>= 1) lossp += __shfl_xor(lossp, off, 64);
  if ((tid & 63) == 0) red[tid >> 6] = lossp;
  __syncthreads();
  if (tid == 0) atomicAdd(acc, red[0] + red[1] + red[2] + red[3]);
}

__global__ void finalize_loss(const float* __restrict__ acc, float* __restrict__ out)
{
  out[(size_t)BB * NC] = acc[0] * (1.f / (float)(BB * NC)) +
                         acc[1] * (1.f / (float)(BB * NG));
}

extern "C" void kernel_launch(void* const* d_in, const int* in_sizes, int n_in,
                              void* d_out, int out_size, void* d_ws, size_t ws_size,
                              hipStream_t stream)
{
  const float* x      = (const float*)d_in[0];
  const int*   cands  = (const int*)  d_in[1];
  const float* labels = (const float*)d_in[2];
  const float* glab   = (const float*)d_in[3];
  const float* W1     = (const float*)d_in[4];
  const float* b1     = (const float*)d_in[5];
  const float* W2     = (const float*)d_in[6];
  const float* b2     = (const float*)d_in[7];
  const float* emb    = (const float*)d_in[8];
  const int*   gy     = (const int*)  d_in[9];
  float* out = (float*)d_out;

  // ws layout (floats): acc[16] | y | h | p1 | p2 | order | sg | sstart |
  // scnt | Sn
  float* ws   = (float*)d_ws;
  float* acc  = ws;
  float* y    = ws + 16;
  float* h    = y + BB * NG;
  float* p1   = h + (size_t)BB * IP1;
  float* p2   = p1 + (size_t)S1 * BB * IP1;
  int* order  = (int*)(p2 + (size_t)S2 * BB * IP2);
  int* sg     = order + NPAIR;
  int* sstart = sg + NPAIR;
  int* scnt   = sstart + NPAIR;
  int* Sn     = scnt + NPAIR;

  hipMemsetAsync(acc, 0, 2 * sizeof(float), stream);

  gemm64<<<IT1 * S1, 256, 0, stream>>>(x, DIN, W1, DIN, NHID, p1, IP1, IT1, DIN, CHD1);
  reduce_act<<<(BB * NHID + 255) / 256, 256, 0, stream>>>(p1, S1, IP1, NHID, b1, h, IP1, 0);

  gemm64<<<IT2 * S2, 256, 0, stream>>>(h, IP1, W2, NHID, NG, p2, IP2, IT2, NHID, CHD2);
  reduce_act<<<(BB * NG + 255) / 256, 256, 0, stream>>>(p2, S2, IP2, NG, b2, y, NG, 1);

  prep512<<<1, NPAIR, 0, stream>>>(y, glab, order, sg, sstart, scnt, Sn, acc);

  score5<<<4096, 256, 0, stream>>>(emb, y, order, sg, sstart, scnt, Sn,
                                   cands, labels, gy, out, acc);

  finalize_loss<<<1, 1, 0, stream>>>(acc, out);
}

// Round 5
// 142.332 us; speedup vs baseline: 1.5378x; 1.5378x over previous
//
#include <hip/hip_runtime.h>
#include <math.h>

static constexpr int BB  = 64;
static constexpr int DIN = 5000;
static constexpr int NHID = 1000;
static constexpr int NG  = 512;
static constexpr int NK  = 8;
static constexpr int NM  = 32;
static constexpr int GS  = 512;
static constexpr int NC  = NK * GS;   // 4096
static constexpr int NPAIR = BB * NK; // 512

// split-K GEMM configs (round-3 proven)
static constexpr int S1 = 16, CHD1 = 320, IT1 = 16, IP1 = 1024;
static constexpr int S2 = 16, CHD2 = 64,  IT2 = 8,  IP2 = 512;

// part[s][b][i] = sum_{d in chunk s} A[b,d] * Bm[i,d]
__global__ __launch_bounds__(256) void gemm64(
    const float* __restrict__ A, int lda,
    const float* __restrict__ Bm, int ldb, int Ireal,
    float* __restrict__ part, int Ipad, int Itiles, int D, int CHD)
{
  __shared__ __align__(16) float xT[32][64];
  __shared__ __align__(16) float wT[32][64];
  const int tid = threadIdx.x;
  const int itile = blockIdx.x % Itiles;
  const int s = blockIdx.x / Itiles;
  const int d_beg = s * CHD;
  const int d_end = min(D, d_beg + CHD);
  const int tx = tid & 15;
  const int ty = tid >> 4;
  float acc[4][4] = {};

  for (int d0 = d_beg; d0 < d_end; d0 += 32) {
#pragma unroll
    for (int q = 0; q < 2; q++) {
      int lin = q * 256 + tid;
      int r = lin >> 3;
      int c4 = (lin & 7) << 2;
      int d = d0 + c4;
      const float* pr = A + (size_t)r * lda;
      float4 v = make_float4(0.f, 0.f, 0.f, 0.f);
      if (d + 4 <= d_end) v = *(const float4*)(pr + d);
      else {
        if (d + 0 < d_end) v.x = pr[d + 0];
        if (d + 1 < d_end) v.y = pr[d + 1];
        if (d + 2 < d_end) v.z = pr[d + 2];
        if (d + 3 < d_end) v.w = pr[d + 3];
      }
      xT[c4 + 0][r] = v.x; xT[c4 + 1][r] = v.y;
      xT[c4 + 2][r] = v.z; xT[c4 + 3][r] = v.w;
    }
#pragma unroll
    for (int q = 0; q < 2; q++) {
      int lin = q * 256 + tid;
      int r = lin >> 3;
      int c4 = (lin & 7) << 2;
      int ib = itile * 64 + r;
      int d = d0 + c4;
      float4 v = make_float4(0.f, 0.f, 0.f, 0.f);
      if (ib < Ireal) {
        const float* pr = Bm + (size_t)ib * ldb;
        if (d + 4 <= d_end) v = *(const float4*)(pr + d);
        else {
          if (d + 0 < d_end) v.x = pr[d + 0];
          if (d + 1 < d_end) v.y = pr[d + 1];
          if (d + 2 < d_end) v.z = pr[d + 2];
          if (d + 3 < d_end) v.w = pr[d + 3];
        }
      }
      wT[c4 + 0][r] = v.x; wT[c4 + 1][r] = v.y;
      wT[c4 + 2][r] = v.z; wT[c4 + 3][r] = v.w;
    }
    __syncthreads();
    const int nn = min(32, d_end - d0);
    if (nn == 32) {
#pragma unroll
      for (int dd = 0; dd < 32; dd++) {
        float4 xv = *(const float4*)&xT[dd][tx << 2];
        float4 wv = *(const float4*)&wT[dd][ty << 2];
        float xr[4] = {xv.x, xv.y, xv.z, xv.w};
        float wr[4] = {wv.x, wv.y, wv.z, wv.w};
#pragma unroll
        for (int a = 0; a < 4; a++)
#pragma unroll
          for (int c = 0; c < 4; c++)
            acc[a][c] = fmaf(xr[a], wr[c], acc[a][c]);
      }
    } else {
      for (int dd = 0; dd < nn; dd++) {
        float4 xv = *(const float4*)&xT[dd][tx << 2];
        float4 wv = *(const float4*)&wT[dd][ty << 2];
        float xr[4] = {xv.x, xv.y, xv.z, xv.w};
        float wr[4] = {wv.x, wv.y, wv.z, wv.w};
#pragma unroll
        for (int a = 0; a < 4; a++)
#pragma unroll
          for (int c = 0; c < 4; c++)
            acc[a][c] = fmaf(xr[a], wr[c], acc[a][c]);
      }
    }
    __syncthreads();
  }

  const int b0 = tx << 2;
  const int i0 = itile * 64 + (ty << 2);
#pragma unroll
  for (int a = 0; a < 4; a++) {
    float4 vv = make_float4(acc[a][0], acc[a][1], acc[a][2], acc[a][3]);
    *(float4*)&part[((size_t)s * BB + (b0 + a)) * Ipad + i0] = vv;
  }
}

__global__ void reduce_act(const float* __restrict__ part, int S, int Ipad, int Ireal,
                           const float* __restrict__ bias, float* __restrict__ out,
                           int ostride, int mode)
{
  int lin = blockIdx.x * blockDim.x + threadIdx.x;
  int n = BB * Ireal;
  if (lin >= n) return;
  int b = lin / Ireal;
  int i = lin - b * Ireal;
  float sum = bias[i];
  for (int s = 0; s < S; s++) sum += part[((size_t)s * BB + b) * Ipad + i];
  if (mode == 0) sum = fmaxf(sum, 0.f);
  else           sum = 1.f / (1.f + expf(-sum));
  out[(size_t)b * ostride + i] = sum;
}

// per-sample top-8 (descending, tie -> lower index) + fused BCE term2
__global__ __launch_bounds__(64) void topk_loss2(
    const float* __restrict__ y, const float* __restrict__ gl,
    int* __restrict__ idxo, float* __restrict__ acc)
{
  const int b = blockIdx.x;
  const int lane = threadIdx.x;
  float v[8];
  float l2 = 0.f;
#pragma unroll
  for (int j = 0; j < 8; j++) {
    int pos = j * 64 + lane;
    float z = y[b * NG + pos];
    v[j] = z;
    float t = gl[b * NG + pos];
    l2 += fmaxf(z, 0.f) + log1pf(expf(-fabsf(z))) - z * t;
  }
  for (int k = 0; k < 8; k++) {
    float bv = -INFINITY;
    int bi = 0x7fffffff;
#pragma unroll
    for (int j = 0; j < 8; j++) {
      int pos = j * 64 + lane;
      if (v[j] > bv) { bv = v[j]; bi = pos; }
    }
#pragma unroll
    for (int off = 32; off >= 1; off >>= 1) {
      float ov = __shfl_xor(bv, off, 64);
      int   oi = __shfl_xor(bi, off, 64);
      if (ov > bv || (ov == bv && oi < bi)) { bv = ov; bi = oi; }
    }
    if (lane == 0) idxo[b * NK + k] = bi;
    if (lane == (bi & 63)) {
      int jj = bi >> 6;
#pragma unroll
      for (int j = 0; j < 8; j++) if (j == jj) v[j] = -INFINITY;
    }
  }
#pragma unroll
  for (int off = 32; off >= 1; off >>= 1) l2 += __shfl_xor(l2, off, 64);
  if (lane == 0) atomicAdd(acc + 1, l2);
}

// deterministic sort of the 512 (b,k) pairs by (group id, pair index)
__global__ __launch_bounds__(512) void sort_pairs(
    const int* __restrict__ idxb, int* __restrict__ order)
{
  __shared__ int gs[NPAIR];
  const int i = threadIdx.x;
  gs[i] = idxb[i];
  __syncthreads();
  const int g = gs[i];
  int pos = 0;
  for (int j = 0; j < NPAIR; j++) {
    int gj = gs[j];
    pos += (gj < g) || (gj == g && j < i);
  }
  order[pos] = i;
}

// duo scoring: block handles 2 consecutive sorted pairs x quarter (128 rows).
// If both pairs share a group (~80% after sort), each emb row is loaded once
// and dotted against both samples' y. XCD-chunked L mapping as in round 3.
__global__ __launch_bounds__(512) void score_duo(
    const float* __restrict__ emb, const float* __restrict__ y,
    const int* __restrict__ order, const int* __restrict__ idxb,
    const int* __restrict__ cands, const float* __restrict__ labels,
    const int* __restrict__ group_y, float* __restrict__ out,
    float* __restrict__ acc)
{
  const int L = (blockIdx.x & 7) * 128 + (blockIdx.x >> 3);  // 0..1023
  const int d = L >> 2;      // duo 0..255
  const int q = L & 3;       // quarter 0..3
  const int pa = order[2 * d], pb = order[2 * d + 1];
  const int ba = pa >> 3, bb = pb >> 3;
  const int ga = idxb[pa], gb = idxb[pb];

  __shared__ __align__(16) float ya[NG];
  __shared__ __align__(16) float yb[NG];
  __shared__ int cida[128];
  __shared__ int cidb[128];
  __shared__ int tga[NM];
  __shared__ int tgb[NM];
  __shared__ float red[8];
  const int tid = threadIdx.x;
  ya[tid] = y[ba * NG + tid];
  yb[tid] = y[bb * NG + tid];
  if (tid < 128) cida[tid] = group_y[ga * GS + q * 128 + tid];
  else if (tid < 256) cidb[tid - 128] = group_y[gb * GS + q * 128 + (tid - 128)];
  else if (tid < 256 + NM) {
    int m = tid - 256;
    tga[m] = labels[ba * NM + m] > 0.5f ? cands[ba * NM + m] : -1;
  } else if (tid < 256 + 2 * NM) {
    int m = tid - 256 - NM;
    tgb[m] = labels[bb * NM + m] > 0.5f ? cands[bb * NM + m] : -1;
  }
  __syncthreads();

  const int l = tid & 15, lg = tid >> 4;  // 32 groups of 16 lanes
  const float4* ya4 = (const float4*)ya;
  const float4* yb4 = (const float4*)yb;
  float lossp = 0.f;

  if (ga == gb) {
    for (int it = 0; it < 4; it++) {
      const int rloc = it * 32 + lg;     // 0..127
      const int row = q * 128 + rloc;
      const int rid = cida[rloc];
      const float4* ep = (const float4*)(emb + (size_t)rid * NG);
      float4 e[8];
#pragma unroll
      for (int seg = 0; seg < 8; seg++) e[seg] = ep[seg * 16 + l];
      float sa = 0.f, sb = 0.f;
#pragma unroll
      for (int seg = 0; seg < 8; seg++) {
        float4 av = ya4[seg * 16 + l];
        float4 bv = yb4[seg * 16 + l];
        sa = fmaf(e[seg].x, av.x, sa); sb = fmaf(e[seg].x, bv.x, sb);
        sa = fmaf(e[seg].y, av.y, sa); sb = fmaf(e[seg].y, bv.y, sb);
        sa = fmaf(e[seg].z, av.z, sa); sb = fmaf(e[seg].z, bv.z, sb);
        sa = fmaf(e[seg].w, av.w, sa); sb = fmaf(e[seg].w, bv.w, sb);
      }
#pragma unroll
      for (int off = 8; off >= 1; off >>= 1) {
        sa += __shfl_xor(sa, off, 64);
        sb += __shfl_xor(sb, off, 64);
      }
      if (l == 0) {
        out[(size_t)pa * GS + row] = sa;
        out[(size_t)pb * GS + row] = sb;
        float nla = 0.f, nlb = 0.f;
#pragma unroll
        for (int m = 0; m < NM; m++) {
          if (rid == tga[m]) nla = 1.f;
          if (rid == tgb[m]) nlb = 1.f;
        }
        lossp += fmaxf(sa, 0.f) + log1pf(expf(-fabsf(sa))) - sa * nla;
        lossp += fmaxf(sb, 0.f) + log1pf(expf(-fabsf(sb))) - sb * nlb;
      }
    }
  } else {
    for (int side = 0; side < 2; side++) {
      const int pp = side ? pb : pa;
      const int* cc = side ? cidb : cida;
      const float4* yy = side ? yb4 : ya4;
      const int* tt = side ? tgb : tga;
      for (int it = 0; it < 4; it++) {
        const int rloc = it * 32 + lg;
        const int row = q * 128 + rloc;
        const int rid = cc[rloc];
        const float4* ep = (const float4*)(emb + (size_t)rid * NG);
        float s = 0.f;
#pragma unroll
        for (int seg = 0; seg < 8; seg++) {
          float4 e = ep[seg * 16 + l];
          float4 yv = yy[seg * 16 + l];
          s = fmaf(e.x, yv.x, s);
          s = fmaf(e.y, yv.y, s);
          s = fmaf(e.z, yv.z, s);
          s = fmaf(e.w, yv.w, s);
        }
#pragma unroll
        for (int off = 8; off >= 1; off >>= 1) s += __shfl_xor(s, off, 64);
        if (l == 0) {
          out[(size_t)pp * GS + row] = s;
          float nl = 0.f;
#pragma unroll
          for (int m = 0; m < NM; m++) if (rid == tt[m]) nl = 1.f;
          lossp += fmaxf(s, 0.f) + log1pf(expf(-fabsf(s))) - s * nl;
        }
      }
    }
  }

#pragma unroll
  for (int off = 32; off >= 1; off >>= 1) lossp += __shfl_xor(lossp, off, 64);
  const int wid = tid >> 6;
  if ((tid & 63) == 0) red[wid] = lossp;
  __syncthreads();
  if (tid == 0) {
    float t = 0.f;
#pragma unroll
    for (int w = 0; w < 8; w++) t += red[w];
    atomicAdd(acc, t);
  }
}

__global__ void finalize_loss(const float* __restrict__ acc, float* __restrict__ out)
{
  out[(size_t)BB * NC] = acc[0] * (1.f / (float)(BB * NC)) +
                         acc[1] * (1.f / (float)(BB * NG));
}

extern "C" void kernel_launch(void* const* d_in, const int* in_sizes, int n_in,
                              void* d_out, int out_size, void* d_ws, size_t ws_size,
                              hipStream_t stream)
{
  const float* x      = (const float*)d_in[0];
  const int*   cands  = (const int*)  d_in[1];
  const float* labels = (const float*)d_in[2];
  const float* glab   = (const float*)d_in[3];
  const float* W1     = (const float*)d_in[4];
  const float* b1     = (const float*)d_in[5];
  const float* W2     = (const float*)d_in[6];
  const float* b2     = (const float*)d_in[7];
  const float* emb    = (const float*)d_in[8];
  const int*   gy     = (const int*)  d_in[9];
  float* out = (float*)d_out;

  float* ws   = (float*)d_ws;
  float* acc  = ws;
  float* y    = ws + 16;
  int*   idxb = (int*)(y + BB * NG);
  float* h    = (float*)(idxb + NPAIR);
  float* p1   = h + (size_t)BB * IP1;
  float* p2   = p1 + (size_t)S1 * BB * IP1;
  int*   order = (int*)(p2 + (size_t)S2 * BB * IP2);

  hipMemsetAsync(acc, 0, 2 * sizeof(float), stream);

  gemm64<<<IT1 * S1, 256, 0, stream>>>(x, DIN, W1, DIN, NHID, p1, IP1, IT1, DIN, CHD1);
  reduce_act<<<(BB * NHID + 255) / 256, 256, 0, stream>>>(p1, S1, IP1, NHID, b1, h, IP1, 0);

  gemm64<<<IT2 * S2, 256, 0, stream>>>(h, IP1, W2, NHID, NG, p2, IP2, IT2, NHID, CHD2);
  reduce_act<<<(BB * NG + 255) / 256, 256, 0, stream>>>(p2, S2, IP2, NG, b2, y, NG, 1);

  topk_loss2<<<BB, 64, 0, stream>>>(y, glab, idxb, acc);

  sort_pairs<<<1, NPAIR, 0, stream>>>(idxb, order);

  score_duo<<<2 * NPAIR, 512, 0, stream>>>(emb, y, order, idxb, cands, labels, gy, out, acc);

  finalize_loss<<<1, 1, 0, stream>>>(acc, out);
}